// Round 11
// baseline (667.865 us; speedup 1.0000x reference)
//
#include <hip/hip_runtime.h>

#define BB   4
#define CC   256
#define NPIX 4096
#define AST2 40    // mfma-core LDS row stride (shorts), 80 B, 16B-aligned
#define YSTR 136   // ygemm LDS row stride (shorts) for K-step 128

typedef __attribute__((ext_vector_type(8)))  short bf16x8;
typedef __attribute__((ext_vector_type(4)))  short short4v;
typedef __attribute__((ext_vector_type(16))) float f32x16;

__device__ __forceinline__ short f2bf(float f) {
    unsigned u = __float_as_uint(f);
    u = u + 0x7fff + ((u >> 16) & 1);   // RNE
    return (short)(u >> 16);
}
__device__ __forceinline__ float bf2f(short s) {
    return __uint_as_float(((unsigned)(unsigned short)s) << 16);
}
__device__ __forceinline__ void split_bf(float v, short& hi, short& lo) {
    hi = f2bf(v);
    lo = f2bf(v - bf2f(hi));
}
__device__ __forceinline__ int cdrow(int r, int l5) {
    return (r & 3) + 8 * (r >> 2) + 4 * l5;   // verified m74/m101 C/D row map
}

// ---------------------------------------------------------------------------
// hi/lo split-bf16 MFMA core: 128x128 tile, K=256, register-prefetch pipelined.
// ---------------------------------------------------------------------------
__device__ __forceinline__ void mfma_core_hilo(
    const short* __restrict__ Ahi, const short* __restrict__ Alo,
    const short* __restrict__ Bhi, const short* __restrict__ Blo,
    f32x16 acc[2][2])
{
    __shared__ short LAh[128 * AST2], LAl[128 * AST2];
    __shared__ short LBh[128 * AST2], LBl[128 * AST2];
    const int t = threadIdx.x;
    const int lane = t & 63, w = t >> 6;
    const int l31 = lane & 31, l5 = lane >> 5;
    const int nq = (w & 1) * 64, mq = (w >> 1) * 64;
    const int sr = t >> 1;
    const int sk = (t & 1) * 16;
    const size_t gs = (size_t)sr * 256 + sk;
    const int ls = sr * AST2 + sk;

    bf16x8 rAh0 = *(const bf16x8*)(Ahi + gs);
    bf16x8 rAh1 = *(const bf16x8*)(Ahi + gs + 8);
    bf16x8 rAl0 = *(const bf16x8*)(Alo + gs);
    bf16x8 rAl1 = *(const bf16x8*)(Alo + gs + 8);
    bf16x8 rBh0 = *(const bf16x8*)(Bhi + gs);
    bf16x8 rBh1 = *(const bf16x8*)(Bhi + gs + 8);
    bf16x8 rBl0 = *(const bf16x8*)(Blo + gs);
    bf16x8 rBl1 = *(const bf16x8*)(Blo + gs + 8);

    for (int k0 = 0; k0 < 256; k0 += 32) {
        __syncthreads();
        *(bf16x8*)&LAh[ls]     = rAh0;
        *(bf16x8*)&LAh[ls + 8] = rAh1;
        *(bf16x8*)&LAl[ls]     = rAl0;
        *(bf16x8*)&LAl[ls + 8] = rAl1;
        *(bf16x8*)&LBh[ls]     = rBh0;
        *(bf16x8*)&LBh[ls + 8] = rBh1;
        *(bf16x8*)&LBl[ls]     = rBl0;
        *(bf16x8*)&LBl[ls + 8] = rBl1;
        __syncthreads();
        if (k0 + 32 < 256) {
            size_t g = gs + k0 + 32;
            rAh0 = *(const bf16x8*)(Ahi + g);
            rAh1 = *(const bf16x8*)(Ahi + g + 8);
            rAl0 = *(const bf16x8*)(Alo + g);
            rAl1 = *(const bf16x8*)(Alo + g + 8);
            rBh0 = *(const bf16x8*)(Bhi + g);
            rBh1 = *(const bf16x8*)(Bhi + g + 8);
            rBl0 = *(const bf16x8*)(Blo + g);
            rBl1 = *(const bf16x8*)(Blo + g + 8);
        }
#pragma unroll
        for (int ks = 0; ks < 2; ks++) {
            bf16x8 ah[2], al[2], bh[2], bl[2];
#pragma unroll
            for (int s = 0; s < 2; s++) {
                int ra = (nq + s * 32 + l31) * AST2 + ks * 16 + l5 * 8;
                int rb = (mq + s * 32 + l31) * AST2 + ks * 16 + l5 * 8;
                ah[s] = *(const bf16x8*)&LAh[ra];
                al[s] = *(const bf16x8*)&LAl[ra];
                bh[s] = *(const bf16x8*)&LBh[rb];
                bl[s] = *(const bf16x8*)&LBl[rb];
            }
#pragma unroll
            for (int s = 0; s < 2; s++)
#pragma unroll
                for (int u = 0; u < 2; u++) {
                    acc[s][u] = __builtin_amdgcn_mfma_f32_32x32x16_bf16(ah[s], bh[u], acc[s][u], 0, 0, 0);
                    acc[s][u] = __builtin_amdgcn_mfma_f32_32x32x16_bf16(ah[s], bl[u], acc[s][u], 0, 0, 0);
                    acc[s][u] = __builtin_amdgcn_mfma_f32_32x32x16_bf16(al[s], bh[u], acc[s][u], 0, 0, 0);
                }
        }
    }
}

// Single-bf16 variant (output GEMM), pipelined.
__device__ __forceinline__ void mfma_core_single(
    const short* __restrict__ A, const short* __restrict__ B, f32x16 acc[2][2])
{
    __shared__ short LA[128 * AST2], LB[128 * AST2];
    const int t = threadIdx.x;
    const int lane = t & 63, w = t >> 6;
    const int l31 = lane & 31, l5 = lane >> 5;
    const int nq = (w & 1) * 64, mq = (w >> 1) * 64;
    const int sr = t >> 1;
    const int sk = (t & 1) * 16;
    const size_t gs = (size_t)sr * 256 + sk;
    const int ls = sr * AST2 + sk;

    bf16x8 rA0 = *(const bf16x8*)(A + gs);
    bf16x8 rA1 = *(const bf16x8*)(A + gs + 8);
    bf16x8 rB0 = *(const bf16x8*)(B + gs);
    bf16x8 rB1 = *(const bf16x8*)(B + gs + 8);

    for (int k0 = 0; k0 < 256; k0 += 32) {
        __syncthreads();
        *(bf16x8*)&LA[ls]     = rA0;
        *(bf16x8*)&LA[ls + 8] = rA1;
        *(bf16x8*)&LB[ls]     = rB0;
        *(bf16x8*)&LB[ls + 8] = rB1;
        __syncthreads();
        if (k0 + 32 < 256) {
            size_t g = gs + k0 + 32;
            rA0 = *(const bf16x8*)(A + g);
            rA1 = *(const bf16x8*)(A + g + 8);
            rB0 = *(const bf16x8*)(B + g);
            rB1 = *(const bf16x8*)(B + g + 8);
        }
#pragma unroll
        for (int ks = 0; ks < 2; ks++) {
            bf16x8 a[2], b[2];
#pragma unroll
            for (int s = 0; s < 2; s++) {
                a[s] = *(const bf16x8*)&LA[(nq + s * 32 + l31) * AST2 + ks * 16 + l5 * 8];
                b[s] = *(const bf16x8*)&LB[(mq + s * 32 + l31) * AST2 + ks * 16 + l5 * 8];
            }
#pragma unroll
            for (int s = 0; s < 2; s++)
#pragma unroll
                for (int u = 0; u < 2; u++)
                    acc[s][u] = __builtin_amdgcn_mfma_f32_32x32x16_bf16(a[s], b[u], acc[s][u], 0, 0, 0);
        }
    }
}

// ---------------- pack kernels ----------------

__global__ __launch_bounds__(256) void pack_w_hilo(
    const float* __restrict__ w0, const float* __restrict__ w1, const float* __restrict__ w2,
    short* __restrict__ whi, short* __restrict__ wlo)
{
    int which = blockIdx.y;
    const float* w = which == 0 ? w0 : which == 1 ? w1 : w2;
    int idx = blockIdx.x * 1024 + threadIdx.x * 4;
    float4 v = *(const float4*)(w + idx);
    short4v h, l;
    short th, tl;
    split_bf(v.x, th, tl); h.x = th; l.x = tl;
    split_bf(v.y, th, tl); h.y = th; l.y = tl;
    split_bf(v.z, th, tl); h.z = th; l.z = tl;
    split_bf(v.w, th, tl); h.w = th; l.w = tl;
    *(short4v*)(whi + which * 65536 + idx) = h;
    *(short4v*)(wlo + which * 65536 + idx) = l;
}

__global__ __launch_bounds__(256) void pack_w_out(
    const float* __restrict__ w1, const float* __restrict__ w2, short* __restrict__ wob)
{
    int which = blockIdx.y;
    const float* w = which == 0 ? w1 : w2;
    int idx = blockIdx.x * 1024 + threadIdx.x * 4;
    float4 v = *(const float4*)(w + idx);
    short4v h;
    h.x = f2bf(v.x); h.y = f2bf(v.y); h.z = f2bf(v.z); h.w = f2bf(v.w);
    *(short4v*)(wob + which * 65536 + idx) = h;
}

// transpose + split: [b][256][4096] fp32 -> [b][4096][256] hi/lo bf16. grid (128,8,4)
__global__ __launch_bounds__(256) void pack_t_split(
    const float* __restrict__ in, short* __restrict__ ohi, short* __restrict__ olo)
{
    __shared__ short Th[32][36], Tl[32][36];
    const int b  = blockIdx.z;
    const int n0 = blockIdx.x * 32;
    const int c0 = blockIdx.y * 32;
    const float* src = in + (size_t)b * CC * NPIX;
    const int t = threadIdx.x;
    const int r = t >> 3, q = t & 7;
    float4 v = *(const float4*)(src + (size_t)(c0 + r) * NPIX + n0 + q * 4);
    short h, l;
    split_bf(v.x, h, l); Th[q * 4 + 0][r] = h; Tl[q * 4 + 0][r] = l;
    split_bf(v.y, h, l); Th[q * 4 + 1][r] = h; Tl[q * 4 + 1][r] = l;
    split_bf(v.z, h, l); Th[q * 4 + 2][r] = h; Tl[q * 4 + 2][r] = l;
    split_bf(v.w, h, l); Th[q * 4 + 3][r] = h; Tl[q * 4 + 3][r] = l;
    __syncthreads();
    short4v oh, ol;
    oh.x = Th[r][q * 4 + 0]; ol.x = Tl[r][q * 4 + 0];
    oh.y = Th[r][q * 4 + 1]; ol.y = Tl[r][q * 4 + 1];
    oh.z = Th[r][q * 4 + 2]; ol.z = Tl[r][q * 4 + 2];
    oh.w = Th[r][q * 4 + 3]; ol.w = Tl[r][q * 4 + 3];
    size_t o = (size_t)b * CC * NPIX + (size_t)(n0 + r) * 256 + c0 + q * 4;
    *(short4v*)(ohi + o) = oh;
    *(short4v*)(olo + o) = ol;
}

// Vt[c][m] = x3b.flat[m*256+c] (already bf16). grid (128,8,4)
__global__ __launch_bounds__(256) void packVt_bf(
    const short* __restrict__ x3b, short* __restrict__ Vt)
{
    __shared__ short T[32][33];
    const int b  = blockIdx.z;
    const int m0 = blockIdx.x * 32;
    const int c0 = blockIdx.y * 32;
    const short* in = x3b + (size_t)b * CC * NPIX;
    short* out = Vt + (size_t)b * CC * NPIX;
    const int t = threadIdx.x;
    const int r = t >> 3, q = t & 7;
    short4v v = *(const short4v*)(in + (size_t)(m0 + r) * CC + c0 + q * 4);
    T[q * 4 + 0][r] = v.x;
    T[q * 4 + 1][r] = v.y;
    T[q * 4 + 2][r] = v.z;
    T[q * 4 + 3][r] = v.w;
    __syncthreads();
    short4v o;
    o.x = T[r][q * 4 + 0];
    o.y = T[r][q * 4 + 1];
    o.z = T[r][q * 4 + 2];
    o.w = T[r][q * 4 + 3];
    *(short4v*)(out + (size_t)(c0 + r) * NPIX + m0 + q * 4) = o;
}

// ---------------- GEMM kernels ----------------

// proj. grid (32, 2, 12). p=0 -> x1 hi/lo, p=1 -> x2 fp32, p=2 -> x3 bf16.
__global__ __launch_bounds__(256) void proj_mfma(
    const short* __restrict__ wphi, const short* __restrict__ wplo,
    const short* __restrict__ xthi, const short* __restrict__ xtlo,
    const float* __restrict__ b_teta, const float* __restrict__ b_fi,
    const float* __restrict__ b_gi,
    short* __restrict__ x1hi, short* __restrict__ x1lo,
    float* __restrict__ x2, short* __restrict__ x3b)
{
    const int z = blockIdx.z, p = z >> 2, b = z & 3;
    const int n0 = blockIdx.x * 128, c0 = blockIdx.y * 128;
    const size_t CN = (size_t)CC * NPIX;
    const short* Ah = wphi + p * 65536 + c0 * 256;
    const short* Al = wplo + p * 65536 + c0 * 256;
    const short* Bh = xthi + (size_t)b * CN + (size_t)n0 * 256;
    const short* Bl = xtlo + (size_t)b * CN + (size_t)n0 * 256;
    const float* bias = p == 0 ? b_teta : p == 1 ? b_fi : b_gi;

    f32x16 acc[2][2] = {};
    mfma_core_hilo(Ah, Al, Bh, Bl, acc);

    const int t = threadIdx.x, lane = t & 63, w = t >> 6;
    const int l31 = lane & 31, l5 = lane >> 5;
    const int aq = (w & 1) * 64, bq = (w >> 1) * 64;
#pragma unroll
    for (int s = 0; s < 2; s++)
#pragma unroll
        for (int u = 0; u < 2; u++)
#pragma unroll
            for (int r = 0; r < 16; r++) {
                int c = c0 + aq + s * 32 + cdrow(r, l5);
                int n = n0 + bq + u * 32 + l31;
                float v = acc[s][u][r] + bias[c];
                size_t o = (size_t)b * CN + (size_t)c * NPIX + n;
                if (p == 0) {
                    short h, l; split_bf(v, h, l);
                    x1hi[o] = h; x1lo[o] = l;
                } else if (p == 1) {
                    x2[o] = v;
                } else {
                    x3b[o] = f2bf(v);
                }
            }
}

// scores + fused column partial stats. grid (32, 32) per batch.
__global__ __launch_bounds__(256) void scores_mfma(
    const short* __restrict__ x1hi, const short* __restrict__ x1lo,
    const short* __restrict__ x2thi, const short* __restrict__ x2tlo,
    float* __restrict__ S, float* __restrict__ pm, float* __restrict__ pl)
{
    const int m0 = blockIdx.x * 128, n0 = blockIdx.y * 128;
    f32x16 acc[2][2] = {};
    mfma_core_hilo(x1hi + (size_t)n0 * 256, x1lo + (size_t)n0 * 256,
                   x2thi + (size_t)m0 * 256, x2tlo + (size_t)m0 * 256, acc);

    const int t = threadIdx.x, lane = t & 63, w = t >> 6;
    const int l31 = lane & 31, l5 = lane >> 5;
    const int aq = (w & 1) * 64, bq = (w >> 1) * 64;
#pragma unroll
    for (int s = 0; s < 2; s++)
#pragma unroll
        for (int u = 0; u < 2; u++)
#pragma unroll
            for (int r = 0; r < 16; r++) {
                int n = n0 + aq + s * 32 + cdrow(r, l5);
                int m = m0 + bq + u * 32 + l31;
                S[(size_t)n * NPIX + m] = acc[s][u][r];
            }

    // column partial stats over this block's 64-row half (member = w&1).
    const int member = w & 1;
#pragma unroll
    for (int u = 0; u < 2; u++) {
        float vmax = -1e30f;
#pragma unroll
        for (int s = 0; s < 2; s++)
#pragma unroll
            for (int r = 0; r < 16; r++) vmax = fmaxf(vmax, acc[s][u][r]);
        float vsum = 0.0f;
#pragma unroll
        for (int s = 0; s < 2; s++)
#pragma unroll
            for (int r = 0; r < 16; r++) vsum += __expf(acc[s][u][r] - vmax);
        // combine with partner lane (lane^32) holding the other 16 rows/stripe
        float vmax2 = __shfl_xor(vmax, 32, 64);
        float vsum2 = __shfl_xor(vsum, 32, 64);
        float mc = fmaxf(vmax, vmax2);
        float sc = vsum * __expf(vmax - mc) + vsum2 * __expf(vmax2 - mc);
        if (l5 == 0) {
            size_t pidx = (size_t)(blockIdx.y * 2 + member) * NPIX + m0 + bq + u * 32 + l31;
            pm[pidx] = mc;
            pl[pidx] = sc;
        }
    }
}

// out: relu(x + bias + W.Y^T), single batch. grid (32, 4)
__global__ __launch_bounds__(256) void out_mfma(
    const short* __restrict__ wob,
    const float* __restrict__ b_o1, const float* __restrict__ b_o2,
    const short* __restrict__ Y1s, const short* __restrict__ Y2s,
    const float* __restrict__ x, float* __restrict__ out, int b)
{
    const int ch0 = blockIdx.y * 128;
    const int pix0 = blockIdx.x * 128;
    const short* W = wob + (ch0 < 256 ? 0 : 65536) + (size_t)(ch0 & 255) * 256;
    const short* Y = (ch0 < 256 ? Y1s : Y2s) + (size_t)pix0 * 256;
    const float* bias = ch0 < 256 ? b_o1 : b_o2;

    f32x16 acc[2][2] = {};
    mfma_core_single(W, Y, acc);

    const int t = threadIdx.x, lane = t & 63, w = t >> 6;
    const int l31 = lane & 31, l5 = lane >> 5;
    const int aq = (w & 1) * 64, bq = (w >> 1) * 64;
#pragma unroll
    for (int s = 0; s < 2; s++)
#pragma unroll
        for (int u = 0; u < 2; u++)
#pragma unroll
            for (int r = 0; r < 16; r++) {
                int ch = ch0 + aq + s * 32 + cdrow(r, l5);
                int pix = pix0 + bq + u * 32 + l31;
                int chm = ch & 255;
                float v = acc[s][u][r] + bias[chm] +
                          x[((size_t)b * CC + chm) * NPIX + pix];
                out[((size_t)b * 2 * CC + ch) * NPIX + pix] = fmaxf(v, 0.0f);
            }
}

// combine 64 col partials. grid (16)
__global__ __launch_bounds__(256) void colstats2_kernel(
    const float* __restrict__ pm, const float* __restrict__ pl,
    float* __restrict__ cm, float* __restrict__ cli)
{
    int col = blockIdx.x * 256 + threadIdx.x;
    float m = -1e30f, l = 0.0f;
    for (int i = 0; i < 64; i++) {
        float m2 = pm[(size_t)i * NPIX + col];
        float l2 = pl[(size_t)i * NPIX + col];
        float mn = fmaxf(m, m2);
        l = l * __expf(m - mn) + l2 * __expf(m2 - mn);
        m = mn;
    }
    cm[col]  = m;
    cli[col] = 1.0f / l;
}

// ---------------- fused row-stats + P materialization ----------------
__global__ __launch_bounds__(256) void rowexpP_kernel(
    const float* __restrict__ S, int n_off,
    const float* __restrict__ colm, const float* __restrict__ colli,
    short* __restrict__ P1, short* __restrict__ P2)
{
    const int row = blockIdx.x;
    const int n = n_off + row;
    const float* sp = S + (size_t)n * NPIX;
    const int t = threadIdx.x;
    const int w = t >> 6, lane = t & 63;
    __shared__ float red[4];

    float4 s4[4];
#pragma unroll
    for (int i = 0; i < 4; i++)
        s4[i] = *(const float4*)(sp + (i * 256 + t) * 4);

    float m = -1e30f;
#pragma unroll
    for (int i = 0; i < 4; i++) {
        m = fmaxf(m, fmaxf(fmaxf(s4[i].x, s4[i].y), fmaxf(s4[i].z, s4[i].w)));
    }
    for (int off = 32; off; off >>= 1) m = fmaxf(m, __shfl_xor(m, off, 64));
    if (lane == 0) red[w] = m;
    __syncthreads();
    m = fmaxf(fmaxf(red[0], red[1]), fmaxf(red[2], red[3]));
    __syncthreads();

    float e[16];
    float sum = 0.0f;
#pragma unroll
    for (int i = 0; i < 4; i++) {
        e[i * 4 + 0] = __expf(s4[i].x - m);
        e[i * 4 + 1] = __expf(s4[i].y - m);
        e[i * 4 + 2] = __expf(s4[i].z - m);
        e[i * 4 + 3] = __expf(s4[i].w - m);
        sum += e[i * 4 + 0] + e[i * 4 + 1] + e[i * 4 + 2] + e[i * 4 + 3];
    }
    for (int off = 32; off; off >>= 1) sum += __shfl_xor(sum, off, 64);
    if (lane == 0) red[w] = sum;
    __syncthreads();
    float rl = 1.0f / (red[0] + red[1] + red[2] + red[3]);

    short* p1 = P1 + (size_t)row * NPIX;
    short* p2 = P2 + (size_t)row * NPIX;
#pragma unroll
    for (int i = 0; i < 4; i++) {
        int idx = (i * 256 + t) * 4;
        float4 cm4 = *(const float4*)(colm + idx);
        float4 cl4 = *(const float4*)(colli + idx);
        short4v a, bvv;
        a.x = f2bf(e[i * 4 + 0] * rl);
        a.y = f2bf(e[i * 4 + 1] * rl);
        a.z = f2bf(e[i * 4 + 2] * rl);
        a.w = f2bf(e[i * 4 + 3] * rl);
        bvv.x = f2bf(__expf(s4[i].x - cm4.x) * cl4.x);
        bvv.y = f2bf(__expf(s4[i].y - cm4.y) * cl4.y);
        bvv.z = f2bf(__expf(s4[i].z - cm4.z) * cl4.z);
        bvv.w = f2bf(__expf(s4[i].w - cm4.w) * cl4.w);
        *(short4v*)(p1 + idx) = a;
        *(short4v*)(p2 + idx) = bvv;
    }
}

// ---------------- Y = P @ Vt^T: 32 rows x 256 c per block ----------------
// grid (128 nT, 2 mode) = 256 blocks. P read exactly once from HBM;
// Vt (2 MB) is L2-resident. K-step 128, register-prefetch pipelined.
// wave w covers c in [w*64, w*64+64): 2 MFMA tiles of 32x32 (acc 32 VGPR).
__global__ __launch_bounds__(256) void ygemm_kernel(
    const short* __restrict__ P1a, const short* __restrict__ P1b,
    const short* __restrict__ P2a, const short* __restrict__ P2b,
    const short* __restrict__ Vt,
    short* __restrict__ Y1s, short* __restrict__ Y2s)
{
    __shared__ short LA[32 * YSTR];    //  8704 B
    __shared__ short LB[256 * YSTR];   // 69632 B
    const int mode = blockIdx.y;
    const int n0 = blockIdx.x * 32;
    const short* Pa_ = mode ? P2a : P1a;
    const short* Pb_ = mode ? P2b : P1b;
    const short* A = (n0 < 2048) ? (Pa_ + (size_t)n0 * NPIX)
                                 : (Pb_ + (size_t)(n0 - 2048) * NPIX);
    const short* B = Vt;

    const int t = threadIdx.x, lane = t & 63, w = t >> 6;
    const int l31 = lane & 31, l5 = lane >> 5;
    const int cw = w * 64;            // wave's c-base
    const int sr = t >> 3;            // staging row 0..31
    const int sk = (t & 7) * 16;      // staging k offset (shorts), 0..112

    // prologue prefetch (k0 = 0)
    bf16x8 pa0 = *(const bf16x8*)(A + (size_t)sr * NPIX + sk);
    bf16x8 pa1 = *(const bf16x8*)(A + (size_t)sr * NPIX + sk + 8);
    bf16x8 pb[16];
#pragma unroll
    for (int i = 0; i < 8; i++) {
        const short* bp = B + (size_t)(i * 32 + sr) * NPIX + sk;
        pb[2 * i]     = *(const bf16x8*)bp;
        pb[2 * i + 1] = *(const bf16x8*)(bp + 8);
    }

    f32x16 acc[2] = {};
    for (int k0 = 0; k0 < NPIX; k0 += 128) {
        __syncthreads();
        *(bf16x8*)&LA[sr * YSTR + sk]     = pa0;
        *(bf16x8*)&LA[sr * YSTR + sk + 8] = pa1;
#pragma unroll
        for (int i = 0; i < 8; i++) {
            *(bf16x8*)&LB[(i * 32 + sr) * YSTR + sk]     = pb[2 * i];
            *(bf16x8*)&LB[(i * 32 + sr) * YSTR + sk + 8] = pb[2 * i + 1];
        }
        __syncthreads();
        if (k0 + 128 < NPIX) {
            size_t g = (size_t)(k0 + 128) + sk;
            pa0 = *(const bf16x8*)(A + (size_t)sr * NPIX + g);
            pa1 = *(const bf16x8*)(A + (size_t)sr * NPIX + g + 8);
#pragma unroll
            for (int i = 0; i < 8; i++) {
                const short* bp = B + (size_t)(i * 32 + sr) * NPIX + g;
                pb[2 * i]     = *(const bf16x8*)bp;
                pb[2 * i + 1] = *(const bf16x8*)(bp + 8);
            }
        }
#pragma unroll
        for (int kc = 0; kc < 8; kc++) {
            bf16x8 af = *(const bf16x8*)&LA[l31 * YSTR + kc * 16 + l5 * 8];
#pragma unroll
            for (int u = 0; u < 2; u++) {
                bf16x8 bf = *(const bf16x8*)&LB[(cw + u * 32 + l31) * YSTR + kc * 16 + l5 * 8];
                acc[u] = __builtin_amdgcn_mfma_f32_32x32x16_bf16(af, bf, acc[u], 0, 0, 0);
            }
        }
    }
    short* Y = mode ? Y2s : Y1s;
#pragma unroll
    for (int u = 0; u < 2; u++)
#pragma unroll
        for (int r = 0; r < 16; r++) {
            int rr = cdrow(r, l5);
            Y[(size_t)(n0 + rr) * CC + cw + u * 32 + l31] = f2bf(acc[u][r]);
        }
}

extern "C" void kernel_launch(void* const* d_in, const int* in_sizes, int n_in,
                              void* d_out, int out_size, void* d_ws, size_t ws_size,
                              hipStream_t stream)
{
    (void)in_sizes; (void)n_in; (void)out_size; (void)ws_size;
    const float* x      = (const float*)d_in[0];
    const float* w_teta = (const float*)d_in[1];
    const float* b_teta = (const float*)d_in[2];
    const float* w_fi   = (const float*)d_in[3];
    const float* b_fi   = (const float*)d_in[4];
    const float* w_gi   = (const float*)d_in[5];
    const float* b_gi   = (const float*)d_in[6];
    const float* w_o1   = (const float*)d_in[7];
    const float* b_o1   = (const float*)d_in[8];
    const float* w_o2   = (const float*)d_in[9];
    const float* b_o2   = (const float*)d_in[10];
    float* out = (float*)d_out;

    const size_t CN = (size_t)CC * NPIX;       // 1M elements
    const size_t HALF = (size_t)2048 * NPIX;   // 8M shorts = 16 MB
    float* ws    = (float*)d_ws;
    // --- persistent regions ---
    float* S     = ws;                          // 64 MB
    short* Pfr   = (short*)(S + (size_t)NPIX * NPIX);  // 32 MB (P1a+P2a)
    short* x1hi  = Pfr + 2 * HALF;              // 8 MB each
    short* x1lo  = x1hi + BB * CN;
    short* x2thi = x1lo + BB * CN;
    short* x2tlo = x2thi + BB * CN;
    short* Vtb   = x2tlo + BB * CN;             // 8 MB
    short* Y1s   = Vtb + BB * CN;               // 2 MB
    short* Y2s   = Y1s + CN;                    // 2 MB
    float* cm    = (float*)(Y2s + CN);
    float* cli   = cm + NPIX;
    float* pm    = cli + NPIX;                  // 64*NPIX = 1 MB
    float* pl    = pm + 64 * NPIX;              // 1 MB
    short* wphi  = (short*)(pl + 64 * NPIX);    // 3*65536
    short* wplo  = wphi + 3 * 65536;
    short* wob   = wplo + 3 * 65536;            // 2*65536
    // --- aliases ---
    short* xthi = (short*)S;                    // pre-phase only (16 MB in S)
    short* xtlo = xthi + BB * CN;
    float* x2   = (float*)Pfr;                  // pre-phase only (16 MB)
    short* x3b  = (short*)(x2 + BB * CN);       // pre-phase only (8 MB)
    // P halves: a-halves in Pfr, b-halves overwrite S's first 32 MB
    short* P1a = Pfr;
    short* P2a = Pfr + HALF;
    short* P1b = (short*)S;
    short* P2b = (short*)S + HALF;

    dim3 blk(256);
    pack_w_hilo<<<dim3(64, 3), blk, 0, stream>>>(w_teta, w_fi, w_gi, wphi, wplo);
    pack_w_out<<<dim3(64, 2), blk, 0, stream>>>(w_o1, w_o2, wob);
    pack_t_split<<<dim3(128, 8, 4), blk, 0, stream>>>(x, xthi, xtlo);

    proj_mfma<<<dim3(32, 2, 12), blk, 0, stream>>>(
        wphi, wplo, xthi, xtlo, b_teta, b_fi, b_gi, x1hi, x1lo, x2, x3b);

    pack_t_split<<<dim3(128, 8, 4), blk, 0, stream>>>(x2, x2thi, x2tlo);
    packVt_bf<<<dim3(128, 8, 4), blk, 0, stream>>>(x3b, Vtb);

    for (int b = 0; b < BB; b++) {
        scores_mfma<<<dim3(32, 32), blk, 0, stream>>>(
            x1hi + b * CN, x1lo + b * CN, x2thi + b * CN, x2tlo + b * CN, S, pm, pl);
        colstats2_kernel<<<dim3(16), blk, 0, stream>>>(pm, pl, cm, cli);
        // half 1: rows [0,2048) -> Pfr ; half 2: rows [2048,4096) -> S base
        rowexpP_kernel<<<dim3(2048), blk, 0, stream>>>(S, 0, cm, cli, P1a, P2a);
        rowexpP_kernel<<<dim3(2048), blk, 0, stream>>>(S, 2048, cm, cli, P1b, P2b);
        ygemm_kernel<<<dim3(128, 2), blk, 0, stream>>>(
            P1a, P1b, P2a, P2b, Vtb + b * CN, Y1s, Y2s);
        out_mfma<<<dim3(32, 4), blk, 0, stream>>>(
            wob, b_o1, b_o2, Y1s, Y2s, x, out, b);
    }
}

// Round 12
// 604.066 us; speedup vs baseline: 1.1056x; 1.1056x over previous
//
#include <hip/hip_runtime.h>

#define BB   4
#define CC   256
#define NPIX 4096
#define AST2 40    // mfma-core LDS row stride (shorts), 80 B, 16B-aligned
#define YST  72    // ygemm LDS row stride (shorts), 144 B, 16B-aligned

typedef __attribute__((ext_vector_type(8)))  short bf16x8;
typedef __attribute__((ext_vector_type(4)))  short short4v;
typedef __attribute__((ext_vector_type(16))) float f32x16;

__device__ __forceinline__ short f2bf(float f) {
    unsigned u = __float_as_uint(f);
    u = u + 0x7fff + ((u >> 16) & 1);   // RNE
    return (short)(u >> 16);
}
__device__ __forceinline__ float bf2f(short s) {
    return __uint_as_float(((unsigned)(unsigned short)s) << 16);
}
__device__ __forceinline__ void split_bf(float v, short& hi, short& lo) {
    hi = f2bf(v);
    lo = f2bf(v - bf2f(hi));
}
__device__ __forceinline__ int cdrow(int r, int l5) {
    return (r & 3) + 8 * (r >> 2) + 4 * l5;   // verified m74/m101 C/D row map
}

// ---------------------------------------------------------------------------
// hi/lo split-bf16 MFMA core: 128x128 tile, K=256, register-prefetch pipelined.
// ---------------------------------------------------------------------------
__device__ __forceinline__ void mfma_core_hilo(
    const short* __restrict__ Ahi, const short* __restrict__ Alo,
    const short* __restrict__ Bhi, const short* __restrict__ Blo,
    f32x16 acc[2][2])
{
    __shared__ short LAh[128 * AST2], LAl[128 * AST2];
    __shared__ short LBh[128 * AST2], LBl[128 * AST2];
    const int t = threadIdx.x;
    const int lane = t & 63, w = t >> 6;
    const int l31 = lane & 31, l5 = lane >> 5;
    const int nq = (w & 1) * 64, mq = (w >> 1) * 64;
    const int sr = t >> 1;
    const int sk = (t & 1) * 16;
    const size_t gs = (size_t)sr * 256 + sk;
    const int ls = sr * AST2 + sk;

    bf16x8 rAh0 = *(const bf16x8*)(Ahi + gs);
    bf16x8 rAh1 = *(const bf16x8*)(Ahi + gs + 8);
    bf16x8 rAl0 = *(const bf16x8*)(Alo + gs);
    bf16x8 rAl1 = *(const bf16x8*)(Alo + gs + 8);
    bf16x8 rBh0 = *(const bf16x8*)(Bhi + gs);
    bf16x8 rBh1 = *(const bf16x8*)(Bhi + gs + 8);
    bf16x8 rBl0 = *(const bf16x8*)(Blo + gs);
    bf16x8 rBl1 = *(const bf16x8*)(Blo + gs + 8);

    for (int k0 = 0; k0 < 256; k0 += 32) {
        __syncthreads();
        *(bf16x8*)&LAh[ls]     = rAh0;
        *(bf16x8*)&LAh[ls + 8] = rAh1;
        *(bf16x8*)&LAl[ls]     = rAl0;
        *(bf16x8*)&LAl[ls + 8] = rAl1;
        *(bf16x8*)&LBh[ls]     = rBh0;
        *(bf16x8*)&LBh[ls + 8] = rBh1;
        *(bf16x8*)&LBl[ls]     = rBl0;
        *(bf16x8*)&LBl[ls + 8] = rBl1;
        __syncthreads();
        if (k0 + 32 < 256) {
            size_t g = gs + k0 + 32;
            rAh0 = *(const bf16x8*)(Ahi + g);
            rAh1 = *(const bf16x8*)(Ahi + g + 8);
            rAl0 = *(const bf16x8*)(Alo + g);
            rAl1 = *(const bf16x8*)(Alo + g + 8);
            rBh0 = *(const bf16x8*)(Bhi + g);
            rBh1 = *(const bf16x8*)(Bhi + g + 8);
            rBl0 = *(const bf16x8*)(Blo + g);
            rBl1 = *(const bf16x8*)(Blo + g + 8);
        }
#pragma unroll
        for (int ks = 0; ks < 2; ks++) {
            bf16x8 ah[2], al[2], bh[2], bl[2];
#pragma unroll
            for (int s = 0; s < 2; s++) {
                int ra = (nq + s * 32 + l31) * AST2 + ks * 16 + l5 * 8;
                int rb = (mq + s * 32 + l31) * AST2 + ks * 16 + l5 * 8;
                ah[s] = *(const bf16x8*)&LAh[ra];
                al[s] = *(const bf16x8*)&LAl[ra];
                bh[s] = *(const bf16x8*)&LBh[rb];
                bl[s] = *(const bf16x8*)&LBl[rb];
            }
#pragma unroll
            for (int s = 0; s < 2; s++)
#pragma unroll
                for (int u = 0; u < 2; u++) {
                    acc[s][u] = __builtin_amdgcn_mfma_f32_32x32x16_bf16(ah[s], bh[u], acc[s][u], 0, 0, 0);
                    acc[s][u] = __builtin_amdgcn_mfma_f32_32x32x16_bf16(ah[s], bl[u], acc[s][u], 0, 0, 0);
                    acc[s][u] = __builtin_amdgcn_mfma_f32_32x32x16_bf16(al[s], bh[u], acc[s][u], 0, 0, 0);
                }
        }
    }
}

// Single-bf16 variant (output GEMM), pipelined.
__device__ __forceinline__ void mfma_core_single(
    const short* __restrict__ A, const short* __restrict__ B, f32x16 acc[2][2])
{
    __shared__ short LA[128 * AST2], LB[128 * AST2];
    const int t = threadIdx.x;
    const int lane = t & 63, w = t >> 6;
    const int l31 = lane & 31, l5 = lane >> 5;
    const int nq = (w & 1) * 64, mq = (w >> 1) * 64;
    const int sr = t >> 1;
    const int sk = (t & 1) * 16;
    const size_t gs = (size_t)sr * 256 + sk;
    const int ls = sr * AST2 + sk;

    bf16x8 rA0 = *(const bf16x8*)(A + gs);
    bf16x8 rA1 = *(const bf16x8*)(A + gs + 8);
    bf16x8 rB0 = *(const bf16x8*)(B + gs);
    bf16x8 rB1 = *(const bf16x8*)(B + gs + 8);

    for (int k0 = 0; k0 < 256; k0 += 32) {
        __syncthreads();
        *(bf16x8*)&LA[ls]     = rA0;
        *(bf16x8*)&LA[ls + 8] = rA1;
        *(bf16x8*)&LB[ls]     = rB0;
        *(bf16x8*)&LB[ls + 8] = rB1;
        __syncthreads();
        if (k0 + 32 < 256) {
            size_t g = gs + k0 + 32;
            rA0 = *(const bf16x8*)(A + g);
            rA1 = *(const bf16x8*)(A + g + 8);
            rB0 = *(const bf16x8*)(B + g);
            rB1 = *(const bf16x8*)(B + g + 8);
        }
#pragma unroll
        for (int ks = 0; ks < 2; ks++) {
            bf16x8 a[2], b[2];
#pragma unroll
            for (int s = 0; s < 2; s++) {
                a[s] = *(const bf16x8*)&LA[(nq + s * 32 + l31) * AST2 + ks * 16 + l5 * 8];
                b[s] = *(const bf16x8*)&LB[(mq + s * 32 + l31) * AST2 + ks * 16 + l5 * 8];
            }
#pragma unroll
            for (int s = 0; s < 2; s++)
#pragma unroll
                for (int u = 0; u < 2; u++)
                    acc[s][u] = __builtin_amdgcn_mfma_f32_32x32x16_bf16(a[s], b[u], acc[s][u], 0, 0, 0);
        }
    }
}

// ---------------- pack kernels ----------------

__global__ __launch_bounds__(256) void pack_w_hilo(
    const float* __restrict__ w0, const float* __restrict__ w1, const float* __restrict__ w2,
    short* __restrict__ whi, short* __restrict__ wlo)
{
    int which = blockIdx.y;
    const float* w = which == 0 ? w0 : which == 1 ? w1 : w2;
    int idx = blockIdx.x * 1024 + threadIdx.x * 4;
    float4 v = *(const float4*)(w + idx);
    short4v h, l;
    short th, tl;
    split_bf(v.x, th, tl); h.x = th; l.x = tl;
    split_bf(v.y, th, tl); h.y = th; l.y = tl;
    split_bf(v.z, th, tl); h.z = th; l.z = tl;
    split_bf(v.w, th, tl); h.w = th; l.w = tl;
    *(short4v*)(whi + which * 65536 + idx) = h;
    *(short4v*)(wlo + which * 65536 + idx) = l;
}

__global__ __launch_bounds__(256) void pack_w_out(
    const float* __restrict__ w1, const float* __restrict__ w2, short* __restrict__ wob)
{
    int which = blockIdx.y;
    const float* w = which == 0 ? w1 : w2;
    int idx = blockIdx.x * 1024 + threadIdx.x * 4;
    float4 v = *(const float4*)(w + idx);
    short4v h;
    h.x = f2bf(v.x); h.y = f2bf(v.y); h.z = f2bf(v.z); h.w = f2bf(v.w);
    *(short4v*)(wob + which * 65536 + idx) = h;
}

// transpose + split: [b][256][4096] fp32 -> [b][4096][256] hi/lo bf16. grid (128,8,4)
__global__ __launch_bounds__(256) void pack_t_split(
    const float* __restrict__ in, short* __restrict__ ohi, short* __restrict__ olo)
{
    __shared__ short Th[32][36], Tl[32][36];
    const int b  = blockIdx.z;
    const int n0 = blockIdx.x * 32;
    const int c0 = blockIdx.y * 32;
    const float* src = in + (size_t)b * CC * NPIX;
    const int t = threadIdx.x;
    const int r = t >> 3, q = t & 7;
    float4 v = *(const float4*)(src + (size_t)(c0 + r) * NPIX + n0 + q * 4);
    short h, l;
    split_bf(v.x, h, l); Th[q * 4 + 0][r] = h; Tl[q * 4 + 0][r] = l;
    split_bf(v.y, h, l); Th[q * 4 + 1][r] = h; Tl[q * 4 + 1][r] = l;
    split_bf(v.z, h, l); Th[q * 4 + 2][r] = h; Tl[q * 4 + 2][r] = l;
    split_bf(v.w, h, l); Th[q * 4 + 3][r] = h; Tl[q * 4 + 3][r] = l;
    __syncthreads();
    short4v oh, ol;
    oh.x = Th[r][q * 4 + 0]; ol.x = Tl[r][q * 4 + 0];
    oh.y = Th[r][q * 4 + 1]; ol.y = Tl[r][q * 4 + 1];
    oh.z = Th[r][q * 4 + 2]; ol.z = Tl[r][q * 4 + 2];
    oh.w = Th[r][q * 4 + 3]; ol.w = Tl[r][q * 4 + 3];
    size_t o = (size_t)b * CC * NPIX + (size_t)(n0 + r) * 256 + c0 + q * 4;
    *(short4v*)(ohi + o) = oh;
    *(short4v*)(olo + o) = ol;
}

// Vt[c][m] = x3b.flat[m*256+c] (already bf16). grid (128,8,4)
__global__ __launch_bounds__(256) void packVt_bf(
    const short* __restrict__ x3b, short* __restrict__ Vt)
{
    __shared__ short T[32][33];
    const int b  = blockIdx.z;
    const int m0 = blockIdx.x * 32;
    const int c0 = blockIdx.y * 32;
    const short* in = x3b + (size_t)b * CC * NPIX;
    short* out = Vt + (size_t)b * CC * NPIX;
    const int t = threadIdx.x;
    const int r = t >> 3, q = t & 7;
    short4v v = *(const short4v*)(in + (size_t)(m0 + r) * CC + c0 + q * 4);
    T[q * 4 + 0][r] = v.x;
    T[q * 4 + 1][r] = v.y;
    T[q * 4 + 2][r] = v.z;
    T[q * 4 + 3][r] = v.w;
    __syncthreads();
    short4v o;
    o.x = T[r][q * 4 + 0];
    o.y = T[r][q * 4 + 1];
    o.z = T[r][q * 4 + 2];
    o.w = T[r][q * 4 + 3];
    *(short4v*)(out + (size_t)(c0 + r) * NPIX + m0 + q * 4) = o;
}

// ---------------- GEMM kernels ----------------

// proj. grid (32, 2, 12). p=0 -> x1 hi/lo, p=1 -> x2 fp32, p=2 -> x3 bf16.
__global__ __launch_bounds__(256) void proj_mfma(
    const short* __restrict__ wphi, const short* __restrict__ wplo,
    const short* __restrict__ xthi, const short* __restrict__ xtlo,
    const float* __restrict__ b_teta, const float* __restrict__ b_fi,
    const float* __restrict__ b_gi,
    short* __restrict__ x1hi, short* __restrict__ x1lo,
    float* __restrict__ x2, short* __restrict__ x3b)
{
    const int z = blockIdx.z, p = z >> 2, b = z & 3;
    const int n0 = blockIdx.x * 128, c0 = blockIdx.y * 128;
    const size_t CN = (size_t)CC * NPIX;
    const short* Ah = wphi + p * 65536 + c0 * 256;
    const short* Al = wplo + p * 65536 + c0 * 256;
    const short* Bh = xthi + (size_t)b * CN + (size_t)n0 * 256;
    const short* Bl = xtlo + (size_t)b * CN + (size_t)n0 * 256;
    const float* bias = p == 0 ? b_teta : p == 1 ? b_fi : b_gi;

    f32x16 acc[2][2] = {};
    mfma_core_hilo(Ah, Al, Bh, Bl, acc);

    const int t = threadIdx.x, lane = t & 63, w = t >> 6;
    const int l31 = lane & 31, l5 = lane >> 5;
    const int aq = (w & 1) * 64, bq = (w >> 1) * 64;
#pragma unroll
    for (int s = 0; s < 2; s++)
#pragma unroll
        for (int u = 0; u < 2; u++)
#pragma unroll
            for (int r = 0; r < 16; r++) {
                int c = c0 + aq + s * 32 + cdrow(r, l5);
                int n = n0 + bq + u * 32 + l31;
                float v = acc[s][u][r] + bias[c];
                size_t o = (size_t)b * CN + (size_t)c * NPIX + n;
                if (p == 0) {
                    short h, l; split_bf(v, h, l);
                    x1hi[o] = h; x1lo[o] = l;
                } else if (p == 1) {
                    x2[o] = v;
                } else {
                    x3b[o] = f2bf(v);
                }
            }
}

// scores + fused column partial stats. grid (32, 32) per batch.
__global__ __launch_bounds__(256) void scores_mfma(
    const short* __restrict__ x1hi, const short* __restrict__ x1lo,
    const short* __restrict__ x2thi, const short* __restrict__ x2tlo,
    float* __restrict__ S, float* __restrict__ pm, float* __restrict__ pl)
{
    const int m0 = blockIdx.x * 128, n0 = blockIdx.y * 128;
    f32x16 acc[2][2] = {};
    mfma_core_hilo(x1hi + (size_t)n0 * 256, x1lo + (size_t)n0 * 256,
                   x2thi + (size_t)m0 * 256, x2tlo + (size_t)m0 * 256, acc);

    const int t = threadIdx.x, lane = t & 63, w = t >> 6;
    const int l31 = lane & 31, l5 = lane >> 5;
    const int aq = (w & 1) * 64, bq = (w >> 1) * 64;
#pragma unroll
    for (int s = 0; s < 2; s++)
#pragma unroll
        for (int u = 0; u < 2; u++)
#pragma unroll
            for (int r = 0; r < 16; r++) {
                int n = n0 + aq + s * 32 + cdrow(r, l5);
                int m = m0 + bq + u * 32 + l31;
                S[(size_t)n * NPIX + m] = acc[s][u][r];
            }

    // column partial stats over this block's 64-row half (member = w&1).
    const int member = w & 1;
#pragma unroll
    for (int u = 0; u < 2; u++) {
        float vmax = -1e30f;
#pragma unroll
        for (int s = 0; s < 2; s++)
#pragma unroll
            for (int r = 0; r < 16; r++) vmax = fmaxf(vmax, acc[s][u][r]);
        float vsum = 0.0f;
#pragma unroll
        for (int s = 0; s < 2; s++)
#pragma unroll
            for (int r = 0; r < 16; r++) vsum += __expf(acc[s][u][r] - vmax);
        // combine with partner lane (lane^32) holding the other 16 rows/stripe
        float vmax2 = __shfl_xor(vmax, 32, 64);
        float vsum2 = __shfl_xor(vsum, 32, 64);
        float mc = fmaxf(vmax, vmax2);
        float sc = vsum * __expf(vmax - mc) + vsum2 * __expf(vmax2 - mc);
        if (l5 == 0) {
            size_t pidx = (size_t)(blockIdx.y * 2 + member) * NPIX + m0 + bq + u * 32 + l31;
            pm[pidx] = mc;
            pl[pidx] = sc;
        }
    }
}

// out: relu(x + bias + W.Y^T), single batch. grid (32, 4)
__global__ __launch_bounds__(256) void out_mfma(
    const short* __restrict__ wob,
    const float* __restrict__ b_o1, const float* __restrict__ b_o2,
    const short* __restrict__ Y1s, const short* __restrict__ Y2s,
    const float* __restrict__ x, float* __restrict__ out, int b)
{
    const int ch0 = blockIdx.y * 128;
    const int pix0 = blockIdx.x * 128;
    const short* W = wob + (ch0 < 256 ? 0 : 65536) + (size_t)(ch0 & 255) * 256;
    const short* Y = (ch0 < 256 ? Y1s : Y2s) + (size_t)pix0 * 256;
    const float* bias = ch0 < 256 ? b_o1 : b_o2;

    f32x16 acc[2][2] = {};
    mfma_core_single(W, Y, acc);

    const int t = threadIdx.x, lane = t & 63, w = t >> 6;
    const int l31 = lane & 31, l5 = lane >> 5;
    const int aq = (w & 1) * 64, bq = (w >> 1) * 64;
#pragma unroll
    for (int s = 0; s < 2; s++)
#pragma unroll
        for (int u = 0; u < 2; u++)
#pragma unroll
            for (int r = 0; r < 16; r++) {
                int ch = ch0 + aq + s * 32 + cdrow(r, l5);
                int pix = pix0 + bq + u * 32 + l31;
                int chm = ch & 255;
                float v = acc[s][u][r] + bias[chm] +
                          x[((size_t)b * CC + chm) * NPIX + pix];
                out[((size_t)b * 2 * CC + ch) * NPIX + pix] = fmaxf(v, 0.0f);
            }
}

// combine 64 col partials. grid (16)
__global__ __launch_bounds__(256) void colstats2_kernel(
    const float* __restrict__ pm, const float* __restrict__ pl,
    float* __restrict__ cm, float* __restrict__ cli)
{
    int col = blockIdx.x * 256 + threadIdx.x;
    float m = -1e30f, l = 0.0f;
    for (int i = 0; i < 64; i++) {
        float m2 = pm[(size_t)i * NPIX + col];
        float l2 = pl[(size_t)i * NPIX + col];
        float mn = fmaxf(m, m2);
        l = l * __expf(m - mn) + l2 * __expf(m2 - mn);
        m = mn;
    }
    cm[col]  = m;
    cli[col] = 1.0f / l;
}

// ---------------- fused row-stats + P materialization ----------------
__global__ __launch_bounds__(256) void rowexpP_kernel(
    const float* __restrict__ S, int n_off,
    const float* __restrict__ colm, const float* __restrict__ colli,
    short* __restrict__ P1, short* __restrict__ P2)
{
    const int row = blockIdx.x;
    const int n = n_off + row;
    const float* sp = S + (size_t)n * NPIX;
    const int t = threadIdx.x;
    const int w = t >> 6, lane = t & 63;
    __shared__ float red[4];

    float4 s4[4];
#pragma unroll
    for (int i = 0; i < 4; i++)
        s4[i] = *(const float4*)(sp + (i * 256 + t) * 4);

    float m = -1e30f;
#pragma unroll
    for (int i = 0; i < 4; i++) {
        m = fmaxf(m, fmaxf(fmaxf(s4[i].x, s4[i].y), fmaxf(s4[i].z, s4[i].w)));
    }
    for (int off = 32; off; off >>= 1) m = fmaxf(m, __shfl_xor(m, off, 64));
    if (lane == 0) red[w] = m;
    __syncthreads();
    m = fmaxf(fmaxf(red[0], red[1]), fmaxf(red[2], red[3]));
    __syncthreads();

    float e[16];
    float sum = 0.0f;
#pragma unroll
    for (int i = 0; i < 4; i++) {
        e[i * 4 + 0] = __expf(s4[i].x - m);
        e[i * 4 + 1] = __expf(s4[i].y - m);
        e[i * 4 + 2] = __expf(s4[i].z - m);
        e[i * 4 + 3] = __expf(s4[i].w - m);
        sum += e[i * 4 + 0] + e[i * 4 + 1] + e[i * 4 + 2] + e[i * 4 + 3];
    }
    for (int off = 32; off; off >>= 1) sum += __shfl_xor(sum, off, 64);
    if (lane == 0) red[w] = sum;
    __syncthreads();
    float rl = 1.0f / (red[0] + red[1] + red[2] + red[3]);

    short* p1 = P1 + (size_t)row * NPIX;
    short* p2 = P2 + (size_t)row * NPIX;
#pragma unroll
    for (int i = 0; i < 4; i++) {
        int idx = (i * 256 + t) * 4;
        float4 cm4 = *(const float4*)(colm + idx);
        float4 cl4 = *(const float4*)(colli + idx);
        short4v a, bvv;
        a.x = f2bf(e[i * 4 + 0] * rl);
        a.y = f2bf(e[i * 4 + 1] * rl);
        a.z = f2bf(e[i * 4 + 2] * rl);
        a.w = f2bf(e[i * 4 + 3] * rl);
        bvv.x = f2bf(__expf(s4[i].x - cm4.x) * cl4.x);
        bvv.y = f2bf(__expf(s4[i].y - cm4.y) * cl4.y);
        bvv.z = f2bf(__expf(s4[i].z - cm4.z) * cl4.z);
        bvv.w = f2bf(__expf(s4[i].w - cm4.w) * cl4.w);
        *(short4v*)(p1 + idx) = a;
        *(short4v*)(p2 + idx) = bvv;
    }
}

// ---------------- Y = P @ Vt^T: K-split partials ----------------
// grid (64 nT, 4 kq, 2 mode) = 512 blocks (2/CU). Block: 64n x 256c over
// K=1024 (its quarter). P segment read exactly once; Vt L2-hot.
// Wave w: n-stripe (w&1)*32, c-half (w>>1)*128 -> 4 acc tiles 32x32.
// Writes fp32 partial Yp[mode][kq][n][c]; ycombine sums the 4 quarters.
__global__ __launch_bounds__(256) void ygemm_kernel(
    const short* __restrict__ P1a, const short* __restrict__ P1b,
    const short* __restrict__ P2a, const short* __restrict__ P2b,
    const short* __restrict__ Vt, float* __restrict__ Yp)
{
    __shared__ short LA[64 * YST];     //  9216 B
    __shared__ short LB[256 * YST];    // 36864 B
    const int mode = blockIdx.z, kq = blockIdx.y;
    const int n0 = blockIdx.x * 64;
    const short* Pa_ = mode ? P2a : P1a;
    const short* Pb_ = mode ? P2b : P1b;
    const short* A = (n0 < 2048) ? (Pa_ + (size_t)n0 * NPIX)
                                 : (Pb_ + (size_t)(n0 - 2048) * NPIX);
    const short* B = Vt;
    const int kbase = kq * 1024;

    const int t = threadIdx.x, lane = t & 63, w = t >> 6;
    const int l31 = lane & 31, l5 = lane >> 5;
    const int nst = (w & 1) * 32, cb = (w >> 1) * 128;
    const int ar = t >> 2;            // staging row 0..63
    const int ak = (t & 3) * 16;      // staging k offset (shorts)

    // prologue prefetch (step 0)
    bf16x8 pa[2], pb[8];
    {
        const short* ap = A + (size_t)ar * NPIX + kbase + ak;
        pa[0] = *(const bf16x8*)ap;
        pa[1] = *(const bf16x8*)(ap + 8);
#pragma unroll
        for (int i = 0; i < 4; i++) {
            const short* bp = B + (size_t)(i * 64 + ar) * NPIX + kbase + ak;
            pb[2 * i]     = *(const bf16x8*)bp;
            pb[2 * i + 1] = *(const bf16x8*)(bp + 8);
        }
    }

    f32x16 acc[4] = {};
    for (int s = 0; s < 16; s++) {
        __syncthreads();
        *(bf16x8*)&LA[ar * YST + ak]     = pa[0];
        *(bf16x8*)&LA[ar * YST + ak + 8] = pa[1];
#pragma unroll
        for (int i = 0; i < 4; i++) {
            *(bf16x8*)&LB[(i * 64 + ar) * YST + ak]     = pb[2 * i];
            *(bf16x8*)&LB[(i * 64 + ar) * YST + ak + 8] = pb[2 * i + 1];
        }
        __syncthreads();
        if (s + 1 < 16) {
            int kg = kbase + (s + 1) * 64 + ak;
            const short* ap = A + (size_t)ar * NPIX + kg;
            pa[0] = *(const bf16x8*)ap;
            pa[1] = *(const bf16x8*)(ap + 8);
#pragma unroll
            for (int i = 0; i < 4; i++) {
                const short* bp = B + (size_t)(i * 64 + ar) * NPIX + kg;
                pb[2 * i]     = *(const bf16x8*)bp;
                pb[2 * i + 1] = *(const bf16x8*)(bp + 8);
            }
        }
#pragma unroll
        for (int kc = 0; kc < 4; kc++) {
            bf16x8 af = *(const bf16x8*)&LA[(nst + l31) * YST + kc * 16 + l5 * 8];
#pragma unroll
            for (int u = 0; u < 4; u++) {
                bf16x8 bf = *(const bf16x8*)&LB[(cb + u * 32 + l31) * YST + kc * 16 + l5 * 8];
                acc[u] = __builtin_amdgcn_mfma_f32_32x32x16_bf16(af, bf, acc[u], 0, 0, 0);
            }
        }
    }

    float* Yo = Yp + (size_t)(mode * 4 + kq) * ((size_t)NPIX * CC);
#pragma unroll
    for (int u = 0; u < 4; u++)
#pragma unroll
        for (int r = 0; r < 16; r++) {
            int rr = cdrow(r, l5);
            Yo[(size_t)(n0 + nst + rr) * CC + cb + u * 32 + l31] = acc[u][r];
        }
}

// sum 4 K-quarter partials -> bf16 Y. grid (1024, 2)
__global__ __launch_bounds__(256) void ycombine_kernel(
    const float* __restrict__ Yp, short* __restrict__ Y1s, short* __restrict__ Y2s)
{
    const int mode = blockIdx.y;
    const size_t CN = (size_t)NPIX * CC;
    size_t idx = (size_t)blockIdx.x * 1024 + threadIdx.x * 4;
    const float* p = Yp + (size_t)mode * 4 * CN + idx;
    float4 v0 = *(const float4*)p;
    float4 v1 = *(const float4*)(p + CN);
    float4 v2 = *(const float4*)(p + 2 * CN);
    float4 v3 = *(const float4*)(p + 3 * CN);
    short4v o;
    o.x = f2bf(v0.x + v1.x + v2.x + v3.x);
    o.y = f2bf(v0.y + v1.y + v2.y + v3.y);
    o.z = f2bf(v0.z + v1.z + v2.z + v3.z);
    o.w = f2bf(v0.w + v1.w + v2.w + v3.w);
    *(short4v*)((mode ? Y2s : Y1s) + idx) = o;
}

extern "C" void kernel_launch(void* const* d_in, const int* in_sizes, int n_in,
                              void* d_out, int out_size, void* d_ws, size_t ws_size,
                              hipStream_t stream)
{
    (void)in_sizes; (void)n_in; (void)out_size; (void)ws_size;
    const float* x      = (const float*)d_in[0];
    const float* w_teta = (const float*)d_in[1];
    const float* b_teta = (const float*)d_in[2];
    const float* w_fi   = (const float*)d_in[3];
    const float* b_fi   = (const float*)d_in[4];
    const float* w_gi   = (const float*)d_in[5];
    const float* b_gi   = (const float*)d_in[6];
    const float* w_o1   = (const float*)d_in[7];
    const float* b_o1   = (const float*)d_in[8];
    const float* w_o2   = (const float*)d_in[9];
    const float* b_o2   = (const float*)d_in[10];
    float* out = (float*)d_out;

    const size_t CN = (size_t)CC * NPIX;       // 1M elements
    const size_t HALF = (size_t)2048 * NPIX;   // 8M shorts = 16 MB
    float* ws    = (float*)d_ws;
    // --- persistent regions ---
    float* S     = ws;                          // 64 MB
    short* Pfr   = (short*)(S + (size_t)NPIX * NPIX);  // 32 MB (P1a+P2a)
    short* x1hi  = Pfr + 2 * HALF;              // 8 MB each
    short* x1lo  = x1hi + BB * CN;
    short* x2thi = x1lo + BB * CN;
    short* x2tlo = x2thi + BB * CN;
    short* Vtb   = x2tlo + BB * CN;             // 8 MB
    short* Y1s   = Vtb + BB * CN;               // 2 MB
    short* Y2s   = Y1s + CN;                    // 2 MB
    float* cm    = (float*)(Y2s + CN);
    float* cli   = cm + NPIX;
    float* pm    = cli + NPIX;                  // 64*NPIX = 1 MB
    float* pl    = pm + 64 * NPIX;              // 1 MB
    short* wphi  = (short*)(pl + 64 * NPIX);    // 3*65536
    short* wplo  = wphi + 3 * 65536;
    short* wob   = wplo + 3 * 65536;            // 2*65536
    // --- aliases ---
    short* xthi = (short*)S;                    // pre-phase only (16 MB in S)
    short* xtlo = xthi + BB * CN;
    float* x2   = (float*)Pfr;                  // pre-phase only (16 MB)
    short* x3b  = (short*)(x2 + BB * CN);       // pre-phase only (8 MB)
    // P halves: a-halves in Pfr, b-halves overwrite S's first 32 MB
    short* P1a = Pfr;
    short* P2a = Pfr + HALF;
    short* P1b = (short*)S;
    short* P2b = (short*)S + HALF;
    // Y partials (8 x 4 MB fp32) alias S's upper 32 MB — dead after rowexpP
    // half-2 has consumed S rows [2048,4096); rewritten by next scores_mfma.
    float* Yp  = S + (size_t)8 * 1024 * 1024;

    dim3 blk(256);
    pack_w_hilo<<<dim3(64, 3), blk, 0, stream>>>(w_teta, w_fi, w_gi, wphi, wplo);
    pack_w_out<<<dim3(64, 2), blk, 0, stream>>>(w_o1, w_o2, wob);
    pack_t_split<<<dim3(128, 8, 4), blk, 0, stream>>>(x, xthi, xtlo);

    proj_mfma<<<dim3(32, 2, 12), blk, 0, stream>>>(
        wphi, wplo, xthi, xtlo, b_teta, b_fi, b_gi, x1hi, x1lo, x2, x3b);

    pack_t_split<<<dim3(128, 8, 4), blk, 0, stream>>>(x2, x2thi, x2tlo);
    packVt_bf<<<dim3(128, 8, 4), blk, 0, stream>>>(x3b, Vtb);

    for (int b = 0; b < BB; b++) {
        scores_mfma<<<dim3(32, 32), blk, 0, stream>>>(
            x1hi + b * CN, x1lo + b * CN, x2thi + b * CN, x2tlo + b * CN, S, pm, pl);
        colstats2_kernel<<<dim3(16), blk, 0, stream>>>(pm, pl, cm, cli);
        // half 1: rows [0,2048) -> Pfr ; half 2: rows [2048,4096) -> S base
        rowexpP_kernel<<<dim3(2048), blk, 0, stream>>>(S, 0, cm, cli, P1a, P2a);
        rowexpP_kernel<<<dim3(2048), blk, 0, stream>>>(S, 2048, cm, cli, P1b, P2b);
        ygemm_kernel<<<dim3(64, 4, 2), blk, 0, stream>>>(
            P1a, P1b, P2a, P2b, Vtb + b * CN, Yp);
        ycombine_kernel<<<dim3(1024, 2), blk, 0, stream>>>(Yp, Y1s, Y2s);
        out_mfma<<<dim3(32, 4), blk, 0, stream>>>(
            wob, b_o1, b_o2, Y1s, Y2s, x, out, b);
    }
}